// Round 9
// baseline (226.082 us; speedup 1.0000x reference)
//
// BitNetAttention on MI355X (gfx950) — round 9
//  - k_attn: 2 q-tiles per block (512 blocks, all resident; no grid tail),
//    software-pipelined: prologue = passA(qt0); middle = passB(qt0) ∥ passA(qt1)
//    sharing the SAME staged K tile (stores flow during 2/3 of kernel instead
//    of 1/2 — passA compute hides under the 6.6TB/s store wall); epilogue =
//    passB(qt1). Arithmetic order per row identical -> absmax must stay 1.831e-4.
//  - gemm1 out0 stores non-temporal (16MB write-only stream)
//  - rest unchanged from round 8 (223us)

#include <hip/hip_runtime.h>
#include <math.h>

typedef __attribute__((ext_vector_type(8))) short short8;
typedef __attribute__((ext_vector_type(4))) float f32x4;
typedef __attribute__((ext_vector_type(4))) int i32x4;
typedef __attribute__((ext_vector_type(4))) unsigned int u32x4;

#define DEV __device__ __forceinline__

static constexpr int B_ = 2, S_ = 2048, H_ = 16, D_ = 64, DM_ = 1024;
static constexpr int BH_ = B_ * H_;        // 32
static constexpr int NQ_ = B_ * S_;        // 4096
static constexpr size_t OUT0_ELEMS = (size_t)NQ_ * DM_;
static constexpr float LOG2E = 1.4426950408889634f;
static constexpr float A2 = 0.125f * 1.4426950408889634f;

// ---- workspace byte offsets ----
static constexpr size_t OFF_PMAXX = 256;                                   // 128 f32
static constexpr size_t OFF_PSUM  = 1280;                                  // 4x128 f32
static constexpr size_t OFF_PMAXA = 4096;                                  // 512 f32
static constexpr size_t OFF_K2M   = 12288;                                 // 32 f32 (atomicMax)
static constexpr size_t OFF_COS   = 16384;                                 // 2048*32 f32
static constexpr size_t OFF_SIN   = OFF_COS + (size_t)S_ * 32 * 4;
static constexpr size_t OFF_Q2    = OFF_SIN + (size_t)S_ * 32 * 4;         // f32 [bh][2048]
static constexpr size_t OFF_XQ    = (size_t)1 << 20;                       // i8 [4096][1024]
static constexpr size_t OFF_WQ8   = OFF_XQ   + (size_t)NQ_ * DM_;          // i8 [4096][1024]
static constexpr size_t OFF_QB    = OFF_WQ8  + (size_t)4096 * 1024;        // bf16 [bh][s][64]
static constexpr size_t OFF_KB    = OFF_QB   + (size_t)BH_ * S_ * D_ * 2;
static constexpr size_t OFF_VT    = OFF_KB   + (size_t)BH_ * S_ * D_ * 2;  // bf16 [bh][64][s]
static constexpr size_t OFF_APRE  = OFF_VT   + (size_t)BH_ * D_ * S_ * 2;  // f32 [4096][1024]
static constexpr size_t OFF_AQ    = OFF_APRE + (size_t)NQ_ * DM_ * 4;      // i8 [4096][1024]
static constexpr size_t WS_NEED   = OFF_AQ   + (size_t)NQ_ * DM_;          // ~57 MB

DEV unsigned short f2bf(float f) {
  unsigned u = __builtin_bit_cast(unsigned, f);
  return (unsigned short)((u + 0x7fffu + ((u >> 16) & 1u)) >> 16);
}
DEV float bf2f(unsigned short h) {
  unsigned u = ((unsigned)h) << 16;
  return __builtin_bit_cast(float, u);
}
DEV void gload16(const void* g, void* l) {
  __builtin_amdgcn_global_load_lds((const __attribute__((address_space(1))) unsigned int*)g,
                                   (__attribute__((address_space(3))) unsigned int*)l, 16, 0, 0);
}
DEV int q8pack(float4 v, float sc, float lim) {
  int i0 = (int)fminf(fmaxf(rintf(v.x / sc), -lim), lim);
  int i1 = (int)fminf(fmaxf(rintf(v.y / sc), -lim), lim);
  int i2 = (int)fminf(fmaxf(rintf(v.z / sc), -lim), lim);
  int i3 = (int)fminf(fmaxf(rintf(v.w / sc), -lim), lim);
  return (int)(((unsigned)(i0 & 255)) | ((unsigned)(i1 & 255) << 8) |
               ((unsigned)(i2 & 255) << 16) | ((unsigned)(i3 & 255) << 24));
}

// ---------------- fused reductions + rope ----------------
__global__ void k_reduce6(const float* __restrict__ x, const float* __restrict__ w0,
                          const float* __restrict__ w1, const float* __restrict__ w2,
                          const float* __restrict__ w3, float* __restrict__ pmaxx,
                          float* __restrict__ psum, float* __restrict__ cosT,
                          float* __restrict__ sinT) {
  __shared__ float red[256];
  const int y = blockIdx.y;
  if (y == 5) {
    const int i0 = (blockIdx.x * 256 + threadIdx.x) * 2;
#pragma unroll
    for (int t = 0; t < 2; ++t) {
      const int i = i0 + t;
      const int s = i >> 5, f = i & 31;
      double inv = pow(10000.0, -(double)(2 * f) / 64.0);
      float th = (float)s * (float)inv;
      cosT[i] = (float)cos((double)th);
      sinT[i] = (float)sin((double)th);
    }
    return;
  }
  if (y == 0) {
    const float4* xv = (const float4*)x;
    float mv = 0.f;
    for (int i = blockIdx.x * 256 + threadIdx.x; i < 1048576; i += 128 * 256) {
      float4 v = xv[i];
      mv = fmaxf(mv, fmaxf(fmaxf(fabsf(v.x), fabsf(v.y)), fmaxf(fabsf(v.z), fabsf(v.w))));
    }
    red[threadIdx.x] = mv;
    __syncthreads();
    for (int st = 128; st > 0; st >>= 1) {
      if ((int)threadIdx.x < st) red[threadIdx.x] = fmaxf(red[threadIdx.x], red[threadIdx.x + st]);
      __syncthreads();
    }
    if (threadIdx.x == 0) pmaxx[blockIdx.x] = red[0];
  } else {
    const float* wsrc = (y == 1) ? w0 : (y == 2) ? w1 : (y == 3) ? w2 : w3;
    const float4* xv = (const float4*)wsrc;
    float s = 0.f;
    for (int i = blockIdx.x * 256 + threadIdx.x; i < 262144; i += 128 * 256) {
      float4 v = xv[i];
      s += fabsf(v.x) + fabsf(v.y) + fabsf(v.z) + fabsf(v.w);
    }
    red[threadIdx.x] = s;
    __syncthreads();
    for (int st = 128; st > 0; st >>= 1) {
      if ((int)threadIdx.x < st) red[threadIdx.x] += red[threadIdx.x + st];
      __syncthreads();
    }
    if (threadIdx.x == 0) psum[(y - 1) * 128 + blockIdx.x] = red[0];
  }
}

__global__ void k_finalize1(float* __restrict__ wsf, float* __restrict__ k2m) {
  const float* pmax = wsf + OFF_PMAXX / 4;
  const float* psum = wsf + OFF_PSUM / 4;
  const int w = threadIdx.x >> 6, l = threadIdx.x & 63;
  float s = psum[w * 128 + l] + psum[w * 128 + 64 + l];
#pragma unroll
  for (int off = 1; off < 64; off <<= 1) s += __shfl_xor(s, off);
  if (l == 0) wsf[1 + w] = s / 1048576.0f;  // s_wq,s_wk,s_wv,s_wo
  if (w == 0) {
    float m = fmaxf(pmax[l], pmax[l + 64]);
#pragma unroll
    for (int off = 1; off < 64; off <<= 1) m = fmaxf(m, __shfl_xor(m, off));
    if (l == 0) wsf[0] = m / 127.0f;  // s_x
  }
  if (threadIdx.x < 32) k2m[threadIdx.x] = 0.f;
}

// ---------------- fused quantizers ----------------
__global__ void k_quant_all(const float* __restrict__ x, const float* __restrict__ w0,
                            const float* __restrict__ w1, const float* __restrict__ w2,
                            const float* __restrict__ w3, const float* __restrict__ scal,
                            signed char* __restrict__ xq, signed char* __restrict__ wq) {
  const int bid = blockIdx.x;
  if (bid < 4096) {
    const int i = bid * 256 + threadIdx.x;
    const float sc = scal[0];
    ((int*)xq)[i] = q8pack(((const float4*)x)[i], sc, 127.f);
  } else {
    const int wi = bid - 4096;
    const int y = wi >> 10;
    const int i = (wi & 1023) * 256 + threadIdx.x;
    const float* src = (y == 0) ? w0 : (y == 1) ? w1 : (y == 2) ? w2 : w3;
    const float sc = scal[1 + y];
    ((int*)(wq + (size_t)y * 1048576))[i] = q8pack(((const float4*)src)[i], sc, 1.f);
  }
}

// quant of attn output; each block re-reduces pmaxa (hot in L2); block0 publishes s_a
__global__ void k_quant_a8(const float* __restrict__ x, const float* __restrict__ pmaxa,
                           float* __restrict__ wsf, signed char* __restrict__ out) {
  __shared__ float red[256];
  float m = 0.f;
  for (int k = threadIdx.x; k < 512; k += 256) m = fmaxf(m, pmaxa[k]);
  red[threadIdx.x] = m;
  __syncthreads();
  for (int st = 128; st > 0; st >>= 1) {
    if ((int)threadIdx.x < st) red[threadIdx.x] = fmaxf(red[threadIdx.x], red[threadIdx.x + st]);
    __syncthreads();
  }
  const float sc = red[0] / 127.0f;
  if (blockIdx.x == 0 && threadIdx.x == 0) wsf[5] = sc;  // s_a for gemm1 epilogue
  const int i = blockIdx.x * 256 + threadIdx.x;
  ((int*)out)[i] = q8pack(((const float4*)x)[i], sc, 127.f);
}

// ---------------- int8 GEMM: C[M][N] = A[M][1024] * B[N][1024]^T ----------------
// 3-buffer staging, counted vmcnt, XCD-aware block swizzle.
// MODE 0: TM=128 QKV proj (+RoPE, +fused V transpose); MODE 1: TM=64 O proj.
template <int MODE>
__launch_bounds__(256, 3)
__global__ void k_gemm(const signed char* __restrict__ Ag, const signed char* __restrict__ Bg,
                       const float* __restrict__ scal, const float* __restrict__ cosT,
                       const float* __restrict__ sinT, unsigned short* __restrict__ Qb,
                       unsigned short* __restrict__ Kb, unsigned short* __restrict__ Vt,
                       float* __restrict__ q2t, float* __restrict__ k2m, float* __restrict__ Co) {
  constexpr int TM = (MODE == 0) ? 128 : 64;
  constexpr int MT = TM / 32;
  constexpr int NBX = (MODE == 0) ? 24 : 8;   // grid x extent
  constexpr int CPX = (MODE == 0) ? 96 : 64;  // blocks per XCD (nwg/8)
  __shared__ alignas(16) unsigned char As[3][TM * 64];
  __shared__ alignas(16) unsigned char Bs[3][128 * 64];
  const int w = threadIdx.x >> 6, l = threadIdx.x & 63;

  const int bid = (int)blockIdx.x + (int)blockIdx.y * NBX;
  const int nl = (bid & 7) * CPX + (bid >> 3);
  const int mbase = (nl / NBX) * TM, nbase = (nl % NBX) * 128;

  const i32x4 izero = {0, 0, 0, 0};
  i32x4 acc[MT][4];
#pragma unroll
  for (int a = 0; a < MT; ++a)
#pragma unroll
    for (int b = 0; b < 4; ++b) acc[a][b] = izero;

  const int csrc = (l & 3) ^ ((l >> 2) & 3) ^ ((l >> 4) & 3);
  const int r16 = l >> 2;

  auto stage = [&](int kt, int buf) {
#pragma unroll
    for (int i = 0; i < TM / 64; ++i) {
      const int chunk = w * (TM / 64) + i;
      const int grow = mbase + chunk * 16 + r16;
      gload16(Ag + (size_t)grow * 1024 + kt * 64 + csrc * 16, &As[buf][chunk << 10]);
    }
#pragma unroll
    for (int i = 0; i < 2; ++i) {
      const int chunk = w * 2 + i;
      const int grow = nbase + chunk * 16 + r16;
      gload16(Bg + (size_t)grow * 1024 + kt * 64 + csrc * 16, &Bs[buf][chunk << 10]);
    }
  };
  auto wait_lps = [&]() {
    if constexpr (MODE == 0) asm volatile("s_waitcnt vmcnt(4)" ::: "memory");
    else asm volatile("s_waitcnt vmcnt(3)" ::: "memory");
  };

  const int rA0 = (w >> 1) * (TM / 2) + (l & 15);
  const int rB0 = (w & 1) * 64 + (l & 15);
  const int kc = l >> 4;
  auto compute = [&](int buf) {
    const unsigned char* Ab = &As[buf][0];
    const unsigned char* Bb = &Bs[buf][0];
    i32x4 af[MT], bf[4];
#pragma unroll
    for (int t = 0; t < MT; ++t) {
      const int ra = rA0 + t * 16;
      af[t] = *(const i32x4*)(Ab + ra * 64 + ((kc ^ (ra & 3) ^ ((ra >> 2) & 3)) << 4));
    }
#pragma unroll
    for (int t = 0; t < 4; ++t) {
      const int rb = rB0 + t * 16;
      bf[t] = *(const i32x4*)(Bb + rb * 64 + ((kc ^ (rb & 3) ^ ((rb >> 2) & 3)) << 4));
    }
#pragma unroll
    for (int mt = 0; mt < MT; ++mt)
#pragma unroll
      for (int nt = 0; nt < 4; ++nt)
        acc[mt][nt] = __builtin_amdgcn_mfma_i32_16x16x64_i8(af[mt], bf[nt], acc[mt][nt], 0, 0, 0);
  };

  stage(0, 0);
  stage(1, 1);
  wait_lps();
  __syncthreads();
  for (int kt = 0; kt < 16; ++kt) {
    const int cur = kt % 3;
    if (kt < 14) {
      stage(kt + 2, (kt + 2) % 3);
      compute(cur);
      wait_lps();
    } else {
      compute(cur);
      asm volatile("s_waitcnt vmcnt(0)" ::: "memory");
    }
    __syncthreads();
  }

  // epilogue (C layout: col = lane&15, row = (lane>>4)*4 + reg)
  if constexpr (MODE == 0) {
    const int wm = w >> 1, wn = w & 1;
    const int gcolbase = nbase + wn * 64;
    const int section = gcolbase >> 10;  // 0=q 1=k 2=v
    const int h = (gcolbase & 1023) >> 6;
    const float sc = scal[0] * scal[1 + section];
    const int growbase = mbase + wm * 64;
    if (section < 2) {
      unsigned short* Outb = (section == 0) ? Qb : Kb;
      float wmax = 0.f;
#pragma unroll
      for (int mt = 0; mt < MT; ++mt)
#pragma unroll
        for (int r = 0; r < 4; ++r) {
          const int grow = growbase + mt * 16 + ((l >> 4) << 2) + r;
          const int b = grow >> 11, s = grow & 2047;
          const size_t ob = ((size_t)(b * 16 + h) * 2048 + s) * 64;
          float rsq = 0.f;
#pragma unroll
          for (int nt = 0; nt < 2; ++nt) {
            const int d = nt * 16 + (l & 15);
            const float v1 = (float)acc[mt][nt][r] * sc;
            const float v2 = (float)acc[mt][nt + 2][r] * sc;
            const float cv = cosT[s * 32 + d];
            const float sv = sinT[s * 32 + d];
            const unsigned short h1 = f2bf(v1 * cv - v2 * sv);
            const unsigned short h2 = f2bf(v2 * cv + v1 * sv);
            Outb[ob + d] = h1;
            Outb[ob + d + 32] = h2;
            const float o1 = bf2f(h1), o2 = bf2f(h2);
            rsq += o1 * o1 + o2 * o2;
          }
#pragma unroll
          for (int off = 1; off < 16; off <<= 1) rsq += __shfl_xor(rsq, off);
          if (section == 0) {
            if ((l & 15) == 0) q2t[(size_t)(b * 16 + h) * 2048 + s] = rsq;
          } else {
            wmax = fmaxf(wmax, rsq);
          }
        }
      if (section == 1) {
        wmax = fmaxf(wmax, __shfl_xor(wmax, 16));
        wmax = fmaxf(wmax, __shfl_xor(wmax, 32));
        if (l == 0) {
          const int b = growbase >> 11;
          atomicMax((unsigned int*)&k2m[b * 16 + h], __builtin_bit_cast(unsigned int, wmax));
        }
      }
    } else {
      // fused V transpose: wave-local LDS scratch in As
      unsigned short* Tw = (unsigned short*)(&As[0][0]) + w * 2176;  // 32x68
#pragma unroll
      for (int h0 = 0; h0 < 2; ++h0) {
#pragma unroll
        for (int mh = 0; mh < 2; ++mh) {
          const int mt = h0 * 2 + mh;
#pragma unroll
          for (int r = 0; r < 4; ++r) {
            const int srow = mh * 16 + ((l >> 4) << 2) + r;
#pragma unroll
            for (int nt = 0; nt < 4; ++nt)
              Tw[srow * 68 + nt * 16 + (l & 15)] = f2bf((float)acc[mt][nt][r] * sc);
          }
        }
        asm volatile("s_waitcnt lgkmcnt(0)" ::: "memory");
        __builtin_amdgcn_sched_barrier(0);
        const int i = l & 15, dq = l >> 4;
#pragma unroll
        for (int d0 = 0; d0 < 16; ++d0) {
          const int d = d0 * 4 + dq;
          const unsigned a = Tw[(2 * i) * 68 + d];
          const unsigned b2 = Tw[(2 * i + 1) * 68 + d];
          const int sglob = growbase + h0 * 32 + 2 * i;
          const int b = sglob >> 11, s = sglob & 2047;
          *(unsigned*)(Vt + ((size_t)((b * 16 + h) * 64 + d) * 2048 + s)) = a | (b2 << 16);
        }
        asm volatile("s_waitcnt lgkmcnt(0)" ::: "memory");
        __builtin_amdgcn_sched_barrier(0);
      }
    }
  } else {
    const float sc = scal[4] * scal[5];
#pragma unroll
    for (int mt = 0; mt < MT; ++mt)
#pragma unroll
      for (int r = 0; r < 4; ++r) {
        const int grow = mbase + (w >> 1) * (TM / 2) + mt * 16 + ((l >> 4) << 2) + r;
#pragma unroll
        for (int nt = 0; nt < 4; ++nt) {
          const int gcol = nbase + (w & 1) * 64 + nt * 16 + (l & 15);
          __builtin_nontemporal_store((float)acc[mt][nt][r] * sc,
                                      Co + (size_t)grow * 1024 + gcol);
        }
      }
  }
}

// ---------------- attention: 2 q-tiles/block, pipelined A/B ----------------
// LDS union: prologue Ks3 = smem[0..24KB); middle/epilogue Ks2 = smem[0..16KB),
// Vhs = smem[16..32KB), Ps = smem[32..48KB)
__launch_bounds__(256, 3)
__global__ void k_attn(const unsigned short* __restrict__ Qb, const unsigned short* __restrict__ Kb,
                       const unsigned short* __restrict__ Vt, const float* __restrict__ q2t,
                       const float* __restrict__ k2m, float* __restrict__ Wout,
                       float* __restrict__ Apre, float* __restrict__ pmaxa) {
  __shared__ alignas(16) char smem[48 * 1024];

  const int bid = (int)blockIdx.x;                 // 512 blocks
  const int swz = ((bid & 7) << 6) | (bid >> 3);   // 8 XCDs -> 4 heads each
  const int bh = swz >> 4, qp = swz & 15;
  const int qt0 = qp * 2, qt1 = qp * 2 + 1;
  const int w = threadIdx.x >> 6, l = threadIdx.x & 63;

  const unsigned short* Kg = Kb + (size_t)bh * S_ * D_;
  const unsigned short* Vg = Vt + (size_t)bh * D_ * S_;

  short8 aq0[2], aq1[2];
  {
    const int qr = qt0 * 64 + w * 16 + (l & 15);
    const unsigned short* qp_ = Qb + (size_t)bh * S_ * D_ + (size_t)qr * D_ + ((l >> 4) << 3);
    aq0[0] = *(const short8*)qp_;
    aq0[1] = *(const short8*)(qp_ + 32);
    aq1[0] = *(const short8*)(qp_ + 64 * D_);
    aq1[1] = *(const short8*)(qp_ + 64 * D_ + 32);
  }

  float cb0[4], cb1[4];
  {
    const float km = k2m[bh];
#pragma unroll
    for (int r = 0; r < 4; ++r) {
      const int qr = qt0 * 64 + w * 16 + ((l >> 4) << 2) + r;
      cb0[r] = sqrtf(q2t[(size_t)bh * 2048 + qr] * km) * 0.125f * LOG2E;
      cb1[r] = sqrtf(q2t[(size_t)bh * 2048 + qr + 64] * km) * 0.125f * LOG2E;
    }
  }

  const f32x4 vzero = {0.f, 0.f, 0.f, 0.f};
  const int kxor = ((l & 7) << 4) ^ ((l >> 3) << 4);
  const int lxor = ((l << 4) ^ ((l >> 3) << 4));

  auto stageKbuf = [&](int kb, char* dst) {
    const char* baseK = (const char*)(Kg + (size_t)kb * 64 * D_);
#pragma unroll
    for (int i = 0; i < 2; ++i) {
      int j = (w << 1) + i;
      gload16(baseK + (j << 10) + lxor, dst + (j << 10));
    }
  };
  auto qktbuf = [&](const char* Kbase, const short8* aq, f32x4* sa) {
#pragma unroll
    for (int c = 0; c < 2; ++c) {
      const int colb = (c << 6) + ((l >> 4) << 4);
      short8 bk[4];
#pragma unroll
      for (int ct = 0; ct < 4; ++ct) {
        const int rb = (ct << 4) + (l & 15);
        bk[ct] = *(const short8*)(Kbase + rb * 128 + (colb ^ ((rb & 7) << 4)));
      }
#pragma unroll
      for (int ct = 0; ct < 4; ++ct)
        sa[ct] = __builtin_amdgcn_mfma_f32_16x16x32_bf16(aq[c], bk[ct], sa[ct], 0, 0, 0);
    }
  };

  // ===== PROLOGUE: pass A for qt0 (3-buffer K staging) =====
  float lt0[4] = {0.f, 0.f, 0.f, 0.f};
  stageKbuf(0, smem);
  stageKbuf(1, smem + 8192);
  asm volatile("s_waitcnt vmcnt(2)" ::: "memory");
  __syncthreads();
  for (int kb = 0; kb < 32; ++kb) {
    const int cur = kb % 3;
    if (kb < 30) stageKbuf(kb + 2, smem + ((kb + 2) % 3) * 8192);
    f32x4 sa[4];
#pragma unroll
    for (int t = 0; t < 4; ++t) sa[t] = vzero;
    qktbuf(smem + cur * 8192, aq0, sa);
#pragma unroll
    for (int r = 0; r < 4; ++r) {
      lt0[r] += exp2f(fmaf(sa[0][r], A2, -cb0[r])) + exp2f(fmaf(sa[1][r], A2, -cb0[r])) +
                exp2f(fmaf(sa[2][r], A2, -cb0[r])) + exp2f(fmaf(sa[3][r], A2, -cb0[r]));
    }
    if (kb < 31) {
      asm volatile("s_waitcnt vmcnt(2)" ::: "memory");
    } else {
      asm volatile("s_waitcnt vmcnt(0)" ::: "memory");
    }
    __syncthreads();
  }

  float rl0[4];
#pragma unroll
  for (int r = 0; r < 4; ++r) {
    float s = lt0[r];
#pragma unroll
    for (int off = 1; off < 16; off <<= 1) s += __shfl_xor(s, off);
    rl0[r] = 1.0f / s;
  }

  char* KsB = smem;                                // 2 x 8KB
  char* VhsB = smem + 16384;                       // 2 x 8KB
  float* Pw = (float*)(smem + 32768) + w * 1024;   // 4KB per wave
  const size_t wb0 = (size_t)bh * S_ * S_;

  auto stageB = [&](int kb, int buf) {
    const char* baseK = (const char*)(Kg + (size_t)kb * 64 * D_);
#pragma unroll
    for (int i = 0; i < 2; ++i) {
      int j = (w << 1) + i;
      gload16(baseK + (j << 10) + lxor, KsB + buf * 8192 + (j << 10));
      const size_t voff = (size_t)(j * 8 + (l >> 3)) * (S_ * 2) + (size_t)kb * 128 + kxor;
      gload16((const char*)Vg + voff, VhsB + buf * 8192 + (j << 10));
    }
  };
  // pass-B body for one tile: p -> LDS, Wout store, PV accumulate
  auto passB_tile = [&](int kb, int cur, int qt, const float* rl, const float* cbq,
                        const short8* aq, f32x4* oacc) {
    f32x4 sa[4];
#pragma unroll
    for (int t = 0; t < 4; ++t) sa[t] = vzero;
    qktbuf(KsB + cur * 8192, aq, sa);
#pragma unroll
    for (int ct = 0; ct < 4; ++ct) {
#pragma unroll
      for (int r = 0; r < 4; ++r) {
        const float p = exp2f(fmaf(sa[ct][r], A2, -cbq[r])) * rl[r];
        const int prow = ((l >> 4) << 2) + r;
        const int pbyte = (ct * 16 + (l & 15)) << 2;
        *(float*)((char*)Pw + prow * 256 + (pbyte ^ ((prow & 7) << 4))) = p;
      }
    }
    {
      const size_t wrow0 = wb0 + (size_t)(qt * 64 + w * 16) * S_ + (size_t)kb * 64;
#pragma unroll
      for (int i = 0; i < 4; ++i) {
        const int prow = (i << 2) + (l >> 4);
        const int cb2 = (l & 15) << 4;
        const f32x4 f = *(const f32x4*)((const char*)Pw + prow * 256 + (cb2 ^ ((prow & 7) << 4)));
        __builtin_nontemporal_store(
            f, (f32x4*)(Wout + wrow0 + (size_t)prow * S_ + ((l & 15) << 2)));
      }
    }
#pragma unroll
    for (int c = 0; c < 2; ++c) {
      const int arow = l & 15;
      const int abyte = (c << 7) + ((l >> 4) << 5);
      const u32x4 u0 = *(const u32x4*)((const char*)Pw + arow * 256 + (abyte ^ ((arow & 7) << 4)));
      const u32x4 u1 =
          *(const u32x4*)((const char*)Pw + arow * 256 + ((abyte + 16) ^ ((arow & 7) << 4)));
      short8 ph, pl;
#pragma unroll
      for (int j = 0; j < 4; ++j) {
        const unsigned ua = u0[j], ub = u1[j];
        ph[j] = (short)(ua >> 16);
        ph[4 + j] = (short)(ub >> 16);
        const float da = __builtin_bit_cast(float, ua) -
                         __builtin_bit_cast(float, ua & 0xffff0000u);
        const float db = __builtin_bit_cast(float, ub) -
                         __builtin_bit_cast(float, ub & 0xffff0000u);
        pl[j] = (short)(__builtin_bit_cast(unsigned, da) >> 16);
        pl[4 + j] = (short)(__builtin_bit_cast(unsigned, db) >> 16);
      }
      const int colb = (c << 6) + ((l >> 4) << 4);
#pragma unroll
      for (int dt = 0; dt < 4; ++dt) {
        const int rv = (dt << 4) + (l & 15);
        const short8 vh =
            *(const short8*)(VhsB + cur * 8192 + rv * 128 + (colb ^ ((rv & 7) << 4)));
        oacc[dt] = __builtin_amdgcn_mfma_f32_16x16x32_bf16(ph, vh, oacc[dt], 0, 0, 0);
        oacc[dt] = __builtin_amdgcn_mfma_f32_16x16x32_bf16(pl, vh, oacc[dt], 0, 0, 0);
      }
    }
  };

  f32x4 oacc[4];
#pragma unroll
  for (int t = 0; t < 4; ++t) oacc[t] = vzero;
  float lt1[4] = {0.f, 0.f, 0.f, 0.f};

  // ===== MIDDLE: pass B(qt0) ∥ pass A(qt1), shared K tile =====
  stageB(0, 0);
  asm volatile("s_waitcnt vmcnt(0)" ::: "memory");
  __syncthreads();
  for (int kb = 0; kb < 32; ++kb) {
    const int cur = kb & 1;
    if (kb < 31) stageB(kb + 1, cur ^ 1);  // 4 loads/thread issued FIRST
    // pass A for qt1 on the same staged K
    {
      f32x4 sa[4];
#pragma unroll
      for (int t = 0; t < 4; ++t) sa[t] = vzero;
      qktbuf(KsB + cur * 8192, aq1, sa);
#pragma unroll
      for (int r = 0; r < 4; ++r) {
        lt1[r] += exp2f(fmaf(sa[0][r], A2, -cb1[r])) + exp2f(fmaf(sa[1][r], A2, -cb1[r])) +
                  exp2f(fmaf(sa[2][r], A2, -cb1[r])) + exp2f(fmaf(sa[3][r], A2, -cb1[r]));
      }
    }
    passB_tile(kb, cur, qt0, rl0, cb0, aq0, oacc);
    asm volatile("s_waitcnt vmcnt(4)" ::: "memory");
    __syncthreads();
  }

  float rl1[4];
#pragma unroll
  for (int r = 0; r < 4; ++r) {
    float s = lt1[r];
#pragma unroll
    for (int off = 1; off < 16; off <<= 1) s += __shfl_xor(s, off);
    rl1[r] = 1.0f / s;
  }

  // write Apre for qt0, track absmax
  const int b = bh >> 4, h = bh & 15;
  float am = 0.f;
#pragma unroll
  for (int dt = 0; dt < 4; ++dt)
#pragma unroll
    for (int r = 0; r < 4; ++r) {
      const int qr = qt0 * 64 + w * 16 + ((l >> 4) << 2) + r;
      Apre[(size_t)(b * S_ + qr) * DM_ + h * 64 + dt * 16 + (l & 15)] = oacc[dt][r];
      am = fmaxf(am, fabsf(oacc[dt][r]));
    }
#pragma unroll
  for (int t = 0; t < 4; ++t) oacc[t] = vzero;

  // ===== EPILOGUE: pass B for qt1 =====
  stageB(0, 0);
  asm volatile("s_waitcnt vmcnt(0)" ::: "memory");
  __syncthreads();
  for (int kb = 0; kb < 32; ++kb) {
    const int cur = kb & 1;
    if (kb < 31) stageB(kb + 1, cur ^ 1);
    passB_tile(kb, cur, qt1, rl1, cb1, aq1, oacc);
    asm volatile("s_waitcnt vmcnt(4)" ::: "memory");
    __syncthreads();
  }

#pragma unroll
  for (int dt = 0; dt < 4; ++dt)
#pragma unroll
    for (int r = 0; r < 4; ++r) {
      const int qr = qt1 * 64 + w * 16 + ((l >> 4) << 2) + r;
      Apre[(size_t)(b * S_ + qr) * DM_ + h * 64 + dt * 16 + (l & 15)] = oacc[dt][r];
      am = fmaxf(am, fabsf(oacc[dt][r]));
    }
#pragma unroll
  for (int off = 1; off < 64; off <<= 1) am = fmaxf(am, __shfl_xor(am, off));
  __syncthreads();
  float* red = (float*)smem;
  if (l == 0) red[w] = am;
  __syncthreads();
  if (threadIdx.x == 0)
    pmaxa[bid] = fmaxf(fmaxf(red[0], red[1]), fmaxf(red[2], red[3]));
}

// ---------------- launcher ----------------
extern "C" void kernel_launch(void* const* d_in, const int* in_sizes, int n_in, void* d_out,
                              int out_size, void* d_ws, size_t ws_size, hipStream_t stream) {
  const float* hidden = (const float*)d_in[0];
  const float* Wq = (const float*)d_in[1];
  const float* Wk = (const float*)d_in[2];
  const float* Wv = (const float*)d_in[3];
  const float* Wo = (const float*)d_in[4];
  float* out0 = (float*)d_out;
  float* out1 = out0 + OUT0_ELEMS;

  if (ws_size < WS_NEED) return;

  char* ws = (char*)d_ws;
  float* wsf = (float*)ws;
  float* pmaxx = (float*)(ws + OFF_PMAXX);
  float* psum = (float*)(ws + OFF_PSUM);
  float* pmaxa = (float*)(ws + OFF_PMAXA);
  float* k2mp = (float*)(ws + OFF_K2M);
  float* cosT = (float*)(ws + OFF_COS);
  float* sinT = (float*)(ws + OFF_SIN);
  float* q2p = (float*)(ws + OFF_Q2);
  signed char* xq8 = (signed char*)(ws + OFF_XQ);
  signed char* wq8 = (signed char*)(ws + OFF_WQ8);
  unsigned short* Qbp = (unsigned short*)(ws + OFF_QB);
  unsigned short* Kbp = (unsigned short*)(ws + OFF_KB);
  unsigned short* Vtp = (unsigned short*)(ws + OFF_VT);
  float* apre = (float*)(ws + OFF_APRE);
  signed char* aq8 = (signed char*)(ws + OFF_AQ);

  k_reduce6<<<dim3(128, 6), 256, 0, stream>>>(hidden, Wq, Wk, Wv, Wo, pmaxx, psum, cosT, sinT);
  k_finalize1<<<1, 256, 0, stream>>>(wsf, k2mp);
  k_quant_all<<<8192, 256, 0, stream>>>(hidden, Wq, Wk, Wv, Wo, wsf, xq8, wq8);
  k_gemm<0><<<dim3(24, 32), 256, 0, stream>>>(xq8, wq8, wsf, cosT, sinT, Qbp, Kbp, Vtp, q2p, k2mp,
                                              nullptr);
  k_attn<<<512, 256, 0, stream>>>(Qbp, Kbp, Vtp, q2p, k2mp, out1, apre, pmaxa);
  k_quant_a8<<<4096, 256, 0, stream>>>(apre, pmaxa, wsf, aq8);
  k_gemm<1><<<dim3(8, 64), 256, 0, stream>>>(aq8, wq8 + (size_t)3 * 1048576, wsf, nullptr, nullptr,
                                             nullptr, nullptr, nullptr, nullptr, nullptr, out0);
  (void)in_sizes; (void)n_in; (void)out_size;
}

// Round 10
// 222.661 us; speedup vs baseline: 1.0154x; 1.0154x over previous
//
// BitNetAttention on MI355X (gfx950) — round 10
//  - k_attn reverted to the r8 structure (223us proven; r9's 2-qtile pipeline
//    was neutral — blocks already phase-mix naturally across the chip)
//  - k_finalize1 launch deleted: quant_all blocks re-derive scales locally from
//    pmaxx/psum (bit-identical wave-shuffle reduction), designated blocks
//    publish wsf[0..4]; block 0 zeroes k2m. Launches 7 -> 6.
//  - gemm1 out0 stores stay non-temporal.

#include <hip/hip_runtime.h>
#include <math.h>

typedef __attribute__((ext_vector_type(8))) short short8;
typedef __attribute__((ext_vector_type(4))) float f32x4;
typedef __attribute__((ext_vector_type(4))) int i32x4;
typedef __attribute__((ext_vector_type(4))) unsigned int u32x4;

#define DEV __device__ __forceinline__

static constexpr int B_ = 2, S_ = 2048, H_ = 16, D_ = 64, DM_ = 1024;
static constexpr int BH_ = B_ * H_;        // 32
static constexpr int NQ_ = B_ * S_;        // 4096
static constexpr size_t OUT0_ELEMS = (size_t)NQ_ * DM_;
static constexpr float LOG2E = 1.4426950408889634f;
static constexpr float A2 = 0.125f * 1.4426950408889634f;

// ---- workspace byte offsets ----
static constexpr size_t OFF_PMAXX = 256;                                   // 128 f32
static constexpr size_t OFF_PSUM  = 1280;                                  // 4x128 f32
static constexpr size_t OFF_PMAXA = 4096;                                  // 1024 f32
static constexpr size_t OFF_K2M   = 12288;                                 // 32 f32 (atomicMax)
static constexpr size_t OFF_COS   = 16384;                                 // 2048*32 f32
static constexpr size_t OFF_SIN   = OFF_COS + (size_t)S_ * 32 * 4;
static constexpr size_t OFF_Q2    = OFF_SIN + (size_t)S_ * 32 * 4;         // f32 [bh][2048]
static constexpr size_t OFF_XQ    = (size_t)1 << 20;                       // i8 [4096][1024]
static constexpr size_t OFF_WQ8   = OFF_XQ   + (size_t)NQ_ * DM_;          // i8 [4096][1024]
static constexpr size_t OFF_QB    = OFF_WQ8  + (size_t)4096 * 1024;        // bf16 [bh][s][64]
static constexpr size_t OFF_KB    = OFF_QB   + (size_t)BH_ * S_ * D_ * 2;
static constexpr size_t OFF_VT    = OFF_KB   + (size_t)BH_ * S_ * D_ * 2;  // bf16 [bh][64][s]
static constexpr size_t OFF_APRE  = OFF_VT   + (size_t)BH_ * D_ * S_ * 2;  // f32 [4096][1024]
static constexpr size_t OFF_AQ    = OFF_APRE + (size_t)NQ_ * DM_ * 4;      // i8 [4096][1024]
static constexpr size_t WS_NEED   = OFF_AQ   + (size_t)NQ_ * DM_;          // ~57 MB

DEV unsigned short f2bf(float f) {
  unsigned u = __builtin_bit_cast(unsigned, f);
  return (unsigned short)((u + 0x7fffu + ((u >> 16) & 1u)) >> 16);
}
DEV float bf2f(unsigned short h) {
  unsigned u = ((unsigned)h) << 16;
  return __builtin_bit_cast(float, u);
}
DEV void gload16(const void* g, void* l) {
  __builtin_amdgcn_global_load_lds((const __attribute__((address_space(1))) unsigned int*)g,
                                   (__attribute__((address_space(3))) unsigned int*)l, 16, 0, 0);
}
DEV int q8pack(float4 v, float sc, float lim) {
  int i0 = (int)fminf(fmaxf(rintf(v.x / sc), -lim), lim);
  int i1 = (int)fminf(fmaxf(rintf(v.y / sc), -lim), lim);
  int i2 = (int)fminf(fmaxf(rintf(v.z / sc), -lim), lim);
  int i3 = (int)fminf(fmaxf(rintf(v.w / sc), -lim), lim);
  return (int)(((unsigned)(i0 & 255)) | ((unsigned)(i1 & 255) << 8) |
               ((unsigned)(i2 & 255) << 16) | ((unsigned)(i3 & 255) << 24));
}

// ---------------- fused reductions + rope ----------------
__global__ void k_reduce6(const float* __restrict__ x, const float* __restrict__ w0,
                          const float* __restrict__ w1, const float* __restrict__ w2,
                          const float* __restrict__ w3, float* __restrict__ pmaxx,
                          float* __restrict__ psum, float* __restrict__ cosT,
                          float* __restrict__ sinT) {
  __shared__ float red[256];
  const int y = blockIdx.y;
  if (y == 5) {
    const int i0 = (blockIdx.x * 256 + threadIdx.x) * 2;
#pragma unroll
    for (int t = 0; t < 2; ++t) {
      const int i = i0 + t;
      const int s = i >> 5, f = i & 31;
      double inv = pow(10000.0, -(double)(2 * f) / 64.0);
      float th = (float)s * (float)inv;
      cosT[i] = (float)cos((double)th);
      sinT[i] = (float)sin((double)th);
    }
    return;
  }
  if (y == 0) {
    const float4* xv = (const float4*)x;
    float mv = 0.f;
    for (int i = blockIdx.x * 256 + threadIdx.x; i < 1048576; i += 128 * 256) {
      float4 v = xv[i];
      mv = fmaxf(mv, fmaxf(fmaxf(fabsf(v.x), fabsf(v.y)), fmaxf(fabsf(v.z), fabsf(v.w))));
    }
    red[threadIdx.x] = mv;
    __syncthreads();
    for (int st = 128; st > 0; st >>= 1) {
      if ((int)threadIdx.x < st) red[threadIdx.x] = fmaxf(red[threadIdx.x], red[threadIdx.x + st]);
      __syncthreads();
    }
    if (threadIdx.x == 0) pmaxx[blockIdx.x] = red[0];
  } else {
    const float* wsrc = (y == 1) ? w0 : (y == 2) ? w1 : (y == 3) ? w2 : w3;
    const float4* xv = (const float4*)wsrc;
    float s = 0.f;
    for (int i = blockIdx.x * 256 + threadIdx.x; i < 262144; i += 128 * 256) {
      float4 v = xv[i];
      s += fabsf(v.x) + fabsf(v.y) + fabsf(v.z) + fabsf(v.w);
    }
    red[threadIdx.x] = s;
    __syncthreads();
    for (int st = 128; st > 0; st >>= 1) {
      if ((int)threadIdx.x < st) red[threadIdx.x] += red[threadIdx.x + st];
      __syncthreads();
    }
    if (threadIdx.x == 0) psum[(y - 1) * 128 + blockIdx.x] = red[0];
  }
}

// ---------------- fused quantizers (scales re-derived locally; no finalize1) ----------------
__global__ void k_quant_all(const float* __restrict__ x, const float* __restrict__ w0,
                            const float* __restrict__ w1, const float* __restrict__ w2,
                            const float* __restrict__ w3, const float* __restrict__ pmaxx,
                            const float* __restrict__ psum, float* __restrict__ wsf,
                            float* __restrict__ k2m, signed char* __restrict__ xq,
                            signed char* __restrict__ wq) {
  __shared__ float scsh;
  const int bid = blockIdx.x;
  const int l = threadIdx.x & 63;
  if (bid < 4096) {
    if (threadIdx.x < 64) {  // s_x = max(pmaxx)/127, same order as old finalize1
      float m = fmaxf(pmaxx[l], pmaxx[l + 64]);
#pragma unroll
      for (int off = 1; off < 64; off <<= 1) m = fmaxf(m, __shfl_xor(m, off));
      if (threadIdx.x == 0) scsh = m / 127.0f;
    }
    __syncthreads();
    const float sc = scsh;
    const int i = bid * 256 + threadIdx.x;
    ((int*)xq)[i] = q8pack(((const float4*)x)[i], sc, 127.f);
    if (bid == 0) {
      if (threadIdx.x == 0) wsf[0] = sc;            // publish s_x for gemm0
      if (threadIdx.x < 32) k2m[threadIdx.x] = 0.f; // reset for gemm0 atomicMax
    }
  } else {
    const int wi = bid - 4096;
    const int y = wi >> 10;
    if (threadIdx.x < 64) {  // s_w = sum(psum[y])/2^20, bit-identical to finalize1
      float s = psum[y * 128 + l] + psum[y * 128 + 64 + l];
#pragma unroll
      for (int off = 1; off < 64; off <<= 1) s += __shfl_xor(s, off);
      if (threadIdx.x == 0) scsh = s / 1048576.0f;
    }
    __syncthreads();
    const float sc = scsh;
    const int i = (wi & 1023) * 256 + threadIdx.x;
    const float* src = (y == 0) ? w0 : (y == 1) ? w1 : (y == 2) ? w2 : w3;
    ((int*)(wq + (size_t)y * 1048576))[i] = q8pack(((const float4*)src)[i], sc, 1.f);
    if ((wi & 1023) == 0 && threadIdx.x == 0) wsf[1 + y] = sc;  // publish
  }
}

// quant of attn output; each block re-reduces pmaxa; block0 publishes s_a
__global__ void k_quant_a8(const float* __restrict__ x, const float* __restrict__ pmaxa,
                           float* __restrict__ wsf, signed char* __restrict__ out) {
  __shared__ float red[256];
  float m = 0.f;
  for (int k = threadIdx.x; k < 1024; k += 256) m = fmaxf(m, pmaxa[k]);
  red[threadIdx.x] = m;
  __syncthreads();
  for (int st = 128; st > 0; st >>= 1) {
    if ((int)threadIdx.x < st) red[threadIdx.x] = fmaxf(red[threadIdx.x], red[threadIdx.x + st]);
    __syncthreads();
  }
  const float sc = red[0] / 127.0f;
  if (blockIdx.x == 0 && threadIdx.x == 0) wsf[5] = sc;  // s_a for gemm1 epilogue
  const int i = blockIdx.x * 256 + threadIdx.x;
  ((int*)out)[i] = q8pack(((const float4*)x)[i], sc, 127.f);
}

// ---------------- int8 GEMM: C[M][N] = A[M][1024] * B[N][1024]^T ----------------
// 3-buffer staging, counted vmcnt, XCD-aware block swizzle.
// MODE 0: TM=128 QKV proj (+RoPE, +fused V transpose); MODE 1: TM=64 O proj.
template <int MODE>
__launch_bounds__(256, 3)
__global__ void k_gemm(const signed char* __restrict__ Ag, const signed char* __restrict__ Bg,
                       const float* __restrict__ scal, const float* __restrict__ cosT,
                       const float* __restrict__ sinT, unsigned short* __restrict__ Qb,
                       unsigned short* __restrict__ Kb, unsigned short* __restrict__ Vt,
                       float* __restrict__ q2t, float* __restrict__ k2m, float* __restrict__ Co) {
  constexpr int TM = (MODE == 0) ? 128 : 64;
  constexpr int MT = TM / 32;
  constexpr int NBX = (MODE == 0) ? 24 : 8;   // grid x extent
  constexpr int CPX = (MODE == 0) ? 96 : 64;  // blocks per XCD (nwg/8)
  __shared__ alignas(16) unsigned char As[3][TM * 64];
  __shared__ alignas(16) unsigned char Bs[3][128 * 64];
  const int w = threadIdx.x >> 6, l = threadIdx.x & 63;

  const int bid = (int)blockIdx.x + (int)blockIdx.y * NBX;
  const int nl = (bid & 7) * CPX + (bid >> 3);
  const int mbase = (nl / NBX) * TM, nbase = (nl % NBX) * 128;

  const i32x4 izero = {0, 0, 0, 0};
  i32x4 acc[MT][4];
#pragma unroll
  for (int a = 0; a < MT; ++a)
#pragma unroll
    for (int b = 0; b < 4; ++b) acc[a][b] = izero;

  const int csrc = (l & 3) ^ ((l >> 2) & 3) ^ ((l >> 4) & 3);
  const int r16 = l >> 2;

  auto stage = [&](int kt, int buf) {
#pragma unroll
    for (int i = 0; i < TM / 64; ++i) {
      const int chunk = w * (TM / 64) + i;
      const int grow = mbase + chunk * 16 + r16;
      gload16(Ag + (size_t)grow * 1024 + kt * 64 + csrc * 16, &As[buf][chunk << 10]);
    }
#pragma unroll
    for (int i = 0; i < 2; ++i) {
      const int chunk = w * 2 + i;
      const int grow = nbase + chunk * 16 + r16;
      gload16(Bg + (size_t)grow * 1024 + kt * 64 + csrc * 16, &Bs[buf][chunk << 10]);
    }
  };
  auto wait_lps = [&]() {
    if constexpr (MODE == 0) asm volatile("s_waitcnt vmcnt(4)" ::: "memory");
    else asm volatile("s_waitcnt vmcnt(3)" ::: "memory");
  };

  const int rA0 = (w >> 1) * (TM / 2) + (l & 15);
  const int rB0 = (w & 1) * 64 + (l & 15);
  const int kc = l >> 4;
  auto compute = [&](int buf) {
    const unsigned char* Ab = &As[buf][0];
    const unsigned char* Bb = &Bs[buf][0];
    i32x4 af[MT], bf[4];
#pragma unroll
    for (int t = 0; t < MT; ++t) {
      const int ra = rA0 + t * 16;
      af[t] = *(const i32x4*)(Ab + ra * 64 + ((kc ^ (ra & 3) ^ ((ra >> 2) & 3)) << 4));
    }
#pragma unroll
    for (int t = 0; t < 4; ++t) {
      const int rb = rB0 + t * 16;
      bf[t] = *(const i32x4*)(Bb + rb * 64 + ((kc ^ (rb & 3) ^ ((rb >> 2) & 3)) << 4));
    }
#pragma unroll
    for (int mt = 0; mt < MT; ++mt)
#pragma unroll
      for (int nt = 0; nt < 4; ++nt)
        acc[mt][nt] = __builtin_amdgcn_mfma_i32_16x16x64_i8(af[mt], bf[nt], acc[mt][nt], 0, 0, 0);
  };

  stage(0, 0);
  stage(1, 1);
  wait_lps();
  __syncthreads();
  for (int kt = 0; kt < 16; ++kt) {
    const int cur = kt % 3;
    if (kt < 14) {
      stage(kt + 2, (kt + 2) % 3);
      compute(cur);
      wait_lps();
    } else {
      compute(cur);
      asm volatile("s_waitcnt vmcnt(0)" ::: "memory");
    }
    __syncthreads();
  }

  // epilogue (C layout: col = lane&15, row = (lane>>4)*4 + reg)
  if constexpr (MODE == 0) {
    const int wm = w >> 1, wn = w & 1;
    const int gcolbase = nbase + wn * 64;
    const int section = gcolbase >> 10;  // 0=q 1=k 2=v
    const int h = (gcolbase & 1023) >> 6;
    const float sc = scal[0] * scal[1 + section];
    const int growbase = mbase + wm * 64;
    if (section < 2) {
      unsigned short* Outb = (section == 0) ? Qb : Kb;
      float wmax = 0.f;
#pragma unroll
      for (int mt = 0; mt < MT; ++mt)
#pragma unroll
        for (int r = 0; r < 4; ++r) {
          const int grow = growbase + mt * 16 + ((l >> 4) << 2) + r;
          const int b = grow >> 11, s = grow & 2047;
          const size_t ob = ((size_t)(b * 16 + h) * 2048 + s) * 64;
          float rsq = 0.f;
#pragma unroll
          for (int nt = 0; nt < 2; ++nt) {
            const int d = nt * 16 + (l & 15);
            const float v1 = (float)acc[mt][nt][r] * sc;
            const float v2 = (float)acc[mt][nt + 2][r] * sc;
            const float cv = cosT[s * 32 + d];
            const float sv = sinT[s * 32 + d];
            const unsigned short h1 = f2bf(v1 * cv - v2 * sv);
            const unsigned short h2 = f2bf(v2 * cv + v1 * sv);
            Outb[ob + d] = h1;
            Outb[ob + d + 32] = h2;
            const float o1 = bf2f(h1), o2 = bf2f(h2);
            rsq += o1 * o1 + o2 * o2;
          }
#pragma unroll
          for (int off = 1; off < 16; off <<= 1) rsq += __shfl_xor(rsq, off);
          if (section == 0) {
            if ((l & 15) == 0) q2t[(size_t)(b * 16 + h) * 2048 + s] = rsq;
          } else {
            wmax = fmaxf(wmax, rsq);
          }
        }
      if (section == 1) {
        wmax = fmaxf(wmax, __shfl_xor(wmax, 16));
        wmax = fmaxf(wmax, __shfl_xor(wmax, 32));
        if (l == 0) {
          const int b = growbase >> 11;
          atomicMax((unsigned int*)&k2m[b * 16 + h], __builtin_bit_cast(unsigned int, wmax));
        }
      }
    } else {
      // fused V transpose: wave-local LDS scratch in As
      unsigned short* Tw = (unsigned short*)(&As[0][0]) + w * 2176;  // 32x68
#pragma unroll
      for (int h0 = 0; h0 < 2; ++h0) {
#pragma unroll
        for (int mh = 0; mh < 2; ++mh) {
          const int mt = h0 * 2 + mh;
#pragma unroll
          for (int r = 0; r < 4; ++r) {
            const int srow = mh * 16 + ((l >> 4) << 2) + r;
#pragma unroll
            for (int nt = 0; nt < 4; ++nt)
              Tw[srow * 68 + nt * 16 + (l & 15)] = f2bf((float)acc[mt][nt][r] * sc);
          }
        }
        asm volatile("s_waitcnt lgkmcnt(0)" ::: "memory");
        __builtin_amdgcn_sched_barrier(0);
        const int i = l & 15, dq = l >> 4;
#pragma unroll
        for (int d0 = 0; d0 < 16; ++d0) {
          const int d = d0 * 4 + dq;
          const unsigned a = Tw[(2 * i) * 68 + d];
          const unsigned b2 = Tw[(2 * i + 1) * 68 + d];
          const int sglob = growbase + h0 * 32 + 2 * i;
          const int b = sglob >> 11, s = sglob & 2047;
          *(unsigned*)(Vt + ((size_t)((b * 16 + h) * 64 + d) * 2048 + s)) = a | (b2 << 16);
        }
        asm volatile("s_waitcnt lgkmcnt(0)" ::: "memory");
        __builtin_amdgcn_sched_barrier(0);
      }
    }
  } else {
    const float sc = scal[4] * scal[5];
#pragma unroll
    for (int mt = 0; mt < MT; ++mt)
#pragma unroll
      for (int r = 0; r < 4; ++r) {
        const int grow = mbase + (w >> 1) * (TM / 2) + mt * 16 + ((l >> 4) << 2) + r;
#pragma unroll
        for (int nt = 0; nt < 4; ++nt) {
          const int gcol = nbase + (w & 1) * 64 + nt * 16 + (l & 15);
          __builtin_nontemporal_store((float)acc[mt][nt][r] * sc,
                                      Co + (size_t)grow * 1024 + gcol);
        }
      }
  }
}

// ---------------- attention (r8 structure) ----------------
// LDS union: pass A uses Ks3 = smem[0..24KB) (3 K buffers);
// pass B uses Ks2 = smem[0..16KB), Vhs = smem[16..32KB), Ps = smem[32..48KB)
__launch_bounds__(256, 3)
__global__ void k_attn(const unsigned short* __restrict__ Qb, const unsigned short* __restrict__ Kb,
                       const unsigned short* __restrict__ Vt, const float* __restrict__ q2t,
                       const float* __restrict__ k2m, float* __restrict__ Wout,
                       float* __restrict__ Apre, float* __restrict__ pmaxa) {
  __shared__ alignas(16) char smem[48 * 1024];

  const int bid = (int)blockIdx.x;
  const int swz = ((bid & 7) << 7) | (bid >> 3);  // 8 XCDs -> 4 heads each
  const int bh = swz >> 5, qt = swz & 31;
  const int w = threadIdx.x >> 6, l = threadIdx.x & 63;

  const unsigned short* Kg = Kb + (size_t)bh * S_ * D_;
  const unsigned short* Vg = Vt + (size_t)bh * D_ * S_;

  short8 aq[2];
  {
    const int qrow_f = qt * 64 + w * 16 + (l & 15);
    const unsigned short* qp = Qb + (size_t)bh * S_ * D_ + (size_t)qrow_f * D_ + ((l >> 4) << 3);
    aq[0] = *(const short8*)qp;
    aq[1] = *(const short8*)(qp + 32);
  }

  float cb[4];
  {
    const float km = k2m[bh];
#pragma unroll
    for (int r = 0; r < 4; ++r) {
      const int qr = qt * 64 + w * 16 + ((l >> 4) << 2) + r;
      cb[r] = sqrtf(q2t[(size_t)bh * 2048 + qr] * km) * 0.125f * LOG2E;
    }
  }

  const f32x4 vzero = {0.f, 0.f, 0.f, 0.f};
  const int kxor = ((l & 7) << 4) ^ ((l >> 3) << 4);
  const int lxor = ((l << 4) ^ ((l >> 3) << 4));

  auto stageKbuf = [&](int kb, char* dst) {
    const char* baseK = (const char*)(Kg + (size_t)kb * 64 * D_);
#pragma unroll
    for (int i = 0; i < 2; ++i) {
      int j = (w << 1) + i;
      gload16(baseK + (j << 10) + lxor, dst + (j << 10));
    }
  };
  auto qktbuf = [&](const char* Kbase, f32x4* sa) {
#pragma unroll
    for (int c = 0; c < 2; ++c) {
      const int colb = (c << 6) + ((l >> 4) << 4);
      short8 bk[4];
#pragma unroll
      for (int ct = 0; ct < 4; ++ct) {
        const int rb = (ct << 4) + (l & 15);
        bk[ct] = *(const short8*)(Kbase + rb * 128 + (colb ^ ((rb & 7) << 4)));
      }
#pragma unroll
      for (int ct = 0; ct < 4; ++ct)
        sa[ct] = __builtin_amdgcn_mfma_f32_16x16x32_bf16(aq[c], bk[ct], sa[ct], 0, 0, 0);
    }
  };

  // ===== PASS A: 3-buffer K staging, counted vmcnt(2) =====
  float lt[4] = {0.f, 0.f, 0.f, 0.f};
  stageKbuf(0, smem);
  stageKbuf(1, smem + 8192);
  asm volatile("s_waitcnt vmcnt(2)" ::: "memory");
  __syncthreads();
  for (int kb = 0; kb < 32; ++kb) {
    const int cur = kb % 3;
    if (kb < 30) stageKbuf(kb + 2, smem + ((kb + 2) % 3) * 8192);
    f32x4 sa[4];
#pragma unroll
    for (int t = 0; t < 4; ++t) sa[t] = vzero;
    qktbuf(smem + cur * 8192, sa);
#pragma unroll
    for (int r = 0; r < 4; ++r) {
      lt[r] += exp2f(fmaf(sa[0][r], A2, -cb[r])) + exp2f(fmaf(sa[1][r], A2, -cb[r])) +
               exp2f(fmaf(sa[2][r], A2, -cb[r])) + exp2f(fmaf(sa[3][r], A2, -cb[r]));
    }
    if (kb < 31) {
      asm volatile("s_waitcnt vmcnt(2)" ::: "memory");
    } else {
      asm volatile("s_waitcnt vmcnt(0)" ::: "memory");
    }
    __syncthreads();
  }

  float rl[4];
#pragma unroll
  for (int r = 0; r < 4; ++r) {
    float s = lt[r];
#pragma unroll
    for (int off = 1; off < 16; off <<= 1) s += __shfl_xor(s, off);
    rl[r] = 1.0f / s;
  }

  f32x4 oacc[4];
#pragma unroll
  for (int t = 0; t < 4; ++t) oacc[t] = vzero;
  char* KsB = smem;                 // 2 x 8KB
  char* VhsB = smem + 16384;        // 2 x 8KB
  float* Pw = (float*)(smem + 32768) + w * 1024;  // 4KB per wave
  const size_t wb0 = (size_t)bh * S_ * S_;

  auto stageB = [&](int kb, int buf) {
    const char* baseK = (const char*)(Kg + (size_t)kb * 64 * D_);
#pragma unroll
    for (int i = 0; i < 2; ++i) {
      int j = (w << 1) + i;
      gload16(baseK + (j << 10) + lxor, KsB + buf * 8192 + (j << 10));
      const size_t voff = (size_t)(j * 8 + (l >> 3)) * (S_ * 2) + (size_t)kb * 128 + kxor;
      gload16((const char*)Vg + voff, VhsB + buf * 8192 + (j << 10));
    }
  };

  // ===== PASS B =====
  stageB(0, 0);
  asm volatile("s_waitcnt vmcnt(0)" ::: "memory");
  __syncthreads();
  for (int kb = 0; kb < 32; ++kb) {
    const int cur = kb & 1;
    if (kb < 31) stageB(kb + 1, cur ^ 1);  // 4 loads/thread issued FIRST

    f32x4 sa[4];
#pragma unroll
    for (int t = 0; t < 4; ++t) sa[t] = vzero;
    qktbuf(KsB + cur * 8192, sa);

    // p -> wave-private LDS as raw fp32
#pragma unroll
    for (int ct = 0; ct < 4; ++ct) {
#pragma unroll
      for (int r = 0; r < 4; ++r) {
        const float p = exp2f(fmaf(sa[ct][r], A2, -cb[r])) * rl[r];
        const int prow = ((l >> 4) << 2) + r;
        const int pbyte = (ct * 16 + (l & 15)) << 2;
        *(float*)((char*)Pw + prow * 256 + (pbyte ^ ((prow & 7) << 4))) = p;
      }
    }

    // coalesced non-temporal attn-weight store: exact fp32 p
    {
      const size_t wrow0 = wb0 + (size_t)(qt * 64 + w * 16) * S_ + (size_t)kb * 64;
#pragma unroll
      for (int i = 0; i < 4; ++i) {
        const int prow = (i << 2) + (l >> 4);
        const int cb2 = (l & 15) << 4;
        const f32x4 f = *(const f32x4*)((const char*)Pw + prow * 256 + (cb2 ^ ((prow & 7) << 4)));
        __builtin_nontemporal_store(
            f, (f32x4*)(Wout + wrow0 + (size_t)prow * S_ + ((l & 15) << 2)));
      }
    }

    // PV: O += (p_hi + p_lo) * v_hi ; hi/lo via truncation
#pragma unroll
    for (int c = 0; c < 2; ++c) {
      const int arow = l & 15;
      const int abyte = (c << 7) + ((l >> 4) << 5);
      const u32x4 u0 = *(const u32x4*)((const char*)Pw + arow * 256 + (abyte ^ ((arow & 7) << 4)));
      const u32x4 u1 =
          *(const u32x4*)((const char*)Pw + arow * 256 + ((abyte + 16) ^ ((arow & 7) << 4)));
      short8 ph, pl;
#pragma unroll
      for (int j = 0; j < 4; ++j) {
        const unsigned ua = u0[j], ub = u1[j];
        ph[j] = (short)(ua >> 16);
        ph[4 + j] = (short)(ub >> 16);
        const float da = __builtin_bit_cast(float, ua) -
                         __builtin_bit_cast(float, ua & 0xffff0000u);
        const float db = __builtin_bit_cast(float, ub) -
                         __builtin_bit_cast(float, ub & 0xffff0000u);
        pl[j] = (short)(__builtin_bit_cast(unsigned, da) >> 16);
        pl[4 + j] = (short)(__builtin_bit_cast(unsigned, db) >> 16);
      }
      const int colb = (c << 6) + ((l >> 4) << 4);
#pragma unroll
      for (int dt = 0; dt < 4; ++dt) {
        const int rv = (dt << 4) + (l & 15);
        const short8 vh =
            *(const short8*)(VhsB + cur * 8192 + rv * 128 + (colb ^ ((rv & 7) << 4)));
        oacc[dt] = __builtin_amdgcn_mfma_f32_16x16x32_bf16(ph, vh, oacc[dt], 0, 0, 0);
        oacc[dt] = __builtin_amdgcn_mfma_f32_16x16x32_bf16(pl, vh, oacc[dt], 0, 0, 0);
      }
    }
    // counted wait: only the staging loads (older) must land; stores drain freely
    asm volatile("s_waitcnt vmcnt(4)" ::: "memory");
    __syncthreads();
  }

  const int b = bh >> 4, h = bh & 15;
  float am = 0.f;
#pragma unroll
  for (int dt = 0; dt < 4; ++dt)
#pragma unroll
    for (int r = 0; r < 4; ++r) {
      const int qr = qt * 64 + w * 16 + ((l >> 4) << 2) + r;
      Apre[(size_t)(b * S_ + qr) * DM_ + h * 64 + dt * 16 + (l & 15)] = oacc[dt][r];
      am = fmaxf(am, fabsf(oacc[dt][r]));
    }
#pragma unroll
  for (int off = 1; off < 64; off <<= 1) am = fmaxf(am, __shfl_xor(am, off));
  __syncthreads();
  float* red = (float*)smem;
  if (l == 0) red[w] = am;
  __syncthreads();
  if (threadIdx.x == 0)
    pmaxa[bid] = fmaxf(fmaxf(red[0], red[1]), fmaxf(red[2], red[3]));
}

// ---------------- launcher ----------------
extern "C" void kernel_launch(void* const* d_in, const int* in_sizes, int n_in, void* d_out,
                              int out_size, void* d_ws, size_t ws_size, hipStream_t stream) {
  const float* hidden = (const float*)d_in[0];
  const float* Wq = (const float*)d_in[1];
  const float* Wk = (const float*)d_in[2];
  const float* Wv = (const float*)d_in[3];
  const float* Wo = (const float*)d_in[4];
  float* out0 = (float*)d_out;
  float* out1 = out0 + OUT0_ELEMS;

  if (ws_size < WS_NEED) return;

  char* ws = (char*)d_ws;
  float* wsf = (float*)ws;
  float* pmaxx = (float*)(ws + OFF_PMAXX);
  float* psum = (float*)(ws + OFF_PSUM);
  float* pmaxa = (float*)(ws + OFF_PMAXA);
  float* k2mp = (float*)(ws + OFF_K2M);
  float* cosT = (float*)(ws + OFF_COS);
  float* sinT = (float*)(ws + OFF_SIN);
  float* q2p = (float*)(ws + OFF_Q2);
  signed char* xq8 = (signed char*)(ws + OFF_XQ);
  signed char* wq8 = (signed char*)(ws + OFF_WQ8);
  unsigned short* Qbp = (unsigned short*)(ws + OFF_QB);
  unsigned short* Kbp = (unsigned short*)(ws + OFF_KB);
  unsigned short* Vtp = (unsigned short*)(ws + OFF_VT);
  float* apre = (float*)(ws + OFF_APRE);
  signed char* aq8 = (signed char*)(ws + OFF_AQ);

  k_reduce6<<<dim3(128, 6), 256, 0, stream>>>(hidden, Wq, Wk, Wv, Wo, pmaxx, psum, cosT, sinT);
  k_quant_all<<<8192, 256, 0, stream>>>(hidden, Wq, Wk, Wv, Wo, pmaxx, psum, wsf, k2mp, xq8, wq8);
  k_gemm<0><<<dim3(24, 32), 256, 0, stream>>>(xq8, wq8, wsf, cosT, sinT, Qbp, Kbp, Vtp, q2p, k2mp,
                                              nullptr);
  k_attn<<<1024, 256, 0, stream>>>(Qbp, Kbp, Vtp, q2p, k2mp, out1, apre, pmaxa);
  k_quant_a8<<<4096, 256, 0, stream>>>(apre, pmaxa, wsf, aq8);
  k_gemm<1><<<dim3(8, 64), 256, 0, stream>>>(aq8, wq8 + (size_t)3 * 1048576, wsf, nullptr, nullptr,
                                             nullptr, nullptr, nullptr, nullptr, nullptr, out0);
  (void)in_sizes; (void)n_in; (void)out_size;
}